// Round 2
// baseline (620.739 us; speedup 1.0000x reference)
//
#include <hip/hip_runtime.h>
#include <math.h>

// Problem shape (fixed): B=32, S=4096, D=1024, L=1
#define D_DIM 1024
#define S_DIM 4096
#define B_DIM 32
#define M_TOTAL (B_DIM * S_DIM)   // 131072 rows

#define KQ   128                  // K per pipeline phase
#define NPH  8                    // phases (8*128 = 1024)

using short8 = __attribute__((ext_vector_type(8))) short;
using f32x4  = __attribute__((ext_vector_type(4))) float;

// fp32 -> bf16, round-to-nearest-even
static __device__ __forceinline__ unsigned short f2bf(float x) {
    unsigned int u = __float_as_uint(x);
    u += 0x7fffu + ((u >> 16) & 1u);
    return (unsigned short)(u >> 16);
}

// tanh via exp2-backed __expf; ~1e-6 abs err (we need ~1e-3)
static __device__ __forceinline__ float fast_tanh(float x) {
    float e2 = __expf(2.0f * x);
    return 1.0f - 2.0f * __builtin_amdgcn_rcpf(e2 + 1.0f);
}

// ---------------------------------------------------------------------------
// Detect attn_mask dtype: int32 (0/1 -> high bytes of every word are 0)
// vs. bool/uint8 (random 0/1 bytes -> some high byte nonzero).
__global__ __launch_bounds__(256) void mask_detect_kernel(
        const unsigned int* __restrict__ m, int* __restrict__ flag) {
    __shared__ unsigned int red[4];
    int t = threadIdx.x;
    unsigned int acc = 0;
    for (int i = t; i < 32768; i += 256) acc |= (m[i] & 0xFFFFFF00u);
    #pragma unroll
    for (int k = 1; k <= 32; k <<= 1) acc |= __shfl_xor(acc, k, 64);
    if ((t & 63) == 0) red[t >> 6] = acc;
    __syncthreads();
    if (t == 0) flag[0] = ((red[0] | red[1] | red[2] | red[3]) != 0) ? 1 : 0;
}

// ---------------------------------------------------------------------------
// Convert Wa_w [1024][1024] fp32 -> bf16 ([e][d] layout = MFMA B-fragment
// layout: k contiguous per output-col row).
__global__ __launch_bounds__(256) void wconv_kernel(
        const float* __restrict__ W, unsigned short* __restrict__ Wb) {
    int i = blockIdx.x * 256 + threadIdx.x;   // one float4 per thread
    float4 v = ((const float4*)W)[i];
    ushort4 o;
    o.x = f2bf(v.x); o.y = f2bf(v.y); o.z = f2bf(v.z); o.w = f2bf(v.w);
    ((ushort4*)Wb)[i] = o;
}

// ---------------------------------------------------------------------------
// off[b][e] = sum_d h[0][b][d]*Ua_w[e][d] + Ua_b[e] + Wa_b[e]
__global__ __launch_bounds__(256) void off_kernel(
        const float* __restrict__ h, const float* __restrict__ Uw,
        const float* __restrict__ Ub, const float* __restrict__ Wab,
        float* __restrict__ off) {
    int wg   = blockIdx.x * 4 + (threadIdx.x >> 6);
    int lane = threadIdx.x & 63;
    int b = wg >> 10, e = wg & 1023;
    const float4* h4 = (const float4*)(h + (size_t)b * D_DIM);
    const float4* u4 = (const float4*)(Uw + (size_t)e * D_DIM);
    float s = 0.f;
    #pragma unroll
    for (int c = 0; c < 4; ++c) {
        float4 a = h4[c * 64 + lane];
        float4 w = u4[c * 64 + lane];
        s += a.x * w.x + a.y * w.y + a.z * w.z + a.w * w.w;
    }
    #pragma unroll
    for (int m = 32; m; m >>= 1) s += __shfl_xor(s, m, 64);
    if (lane == 0) off[b * D_DIM + e] = s + Ub[e] + Wab[e];
}

// ---------------------------------------------------------------------------
// Fused: scores[row] = sum_e Va[e] * tanh( (A@W^T)[row][e] + off[b][e] )
//
// 16 waves (1024 thr) per block; block = 64 rows x 1024 cols; wave w owns
// cols [w*64, w*64+64). K pipelined in 8 phases of 128 through a 2x16KB
// double-buffered swizzled LDS A-panel. Per phase: issue next-phase global
// loads (T14 issue-early), 64 MFMAs from LDS + L2-resident bf16 W, then
// convert+ds_write (write-late), one barrier. acc persists across phases.
__global__ __launch_bounds__(1024, 4) void score_kernel(
        const float* __restrict__ A,            // [M][1024] fp32
        const unsigned short* __restrict__ Wb,  // [1024][1024] bf16 ([e][k])
        const float* __restrict__ off,          // [32][1024]
        const float* __restrict__ Va,           // [1024]
        float* __restrict__ scores)             // [M]
{
    __shared__ short As[2][64 * KQ];    // 2 x 16 KiB, XOR-swizzled rows
    __shared__ float score_lds[64];

    const int t    = threadIdx.x;
    const int row0 = blockIdx.x * 64;
    const int b    = row0 >> 12;        // 4096 rows per batch

    if (t < 64) score_lds[t] = 0.f;

    const int wave = t >> 6, lane = t & 63;
    const int l15 = lane & 15, lhi = lane >> 4;
    const int e0 = wave * 64;

    // per-thread staging slot: one short8 per phase
    const int sr = t >> 4;              // row 0..63
    const int sk = (t & 15) * 8;        // k-base 0..120
    const float* Asrc = A + (size_t)(row0 + sr) * D_DIM + sk;
    const int sidx = sr * KQ + (sk ^ ((sr & 7) << 3));   // ushort units

    f32x4 acc[4][4];
    #pragma unroll
    for (int rf = 0; rf < 4; ++rf)
        #pragma unroll
        for (int cf = 0; cf < 4; ++cf) acc[rf][cf] = (f32x4){0.f, 0.f, 0.f, 0.f};

    // ---- prologue: stage phase 0 ----
    {
        float4 v0 = *(const float4*)(Asrc + 0);
        float4 v1 = *(const float4*)(Asrc + 4);
        short8 pk;
        pk[0] = (short)f2bf(v0.x); pk[1] = (short)f2bf(v0.y);
        pk[2] = (short)f2bf(v0.z); pk[3] = (short)f2bf(v0.w);
        pk[4] = (short)f2bf(v1.x); pk[5] = (short)f2bf(v1.y);
        pk[6] = (short)f2bf(v1.z); pk[7] = (short)f2bf(v1.w);
        *(short8*)(&As[0][sidx]) = pk;
    }
    __syncthreads();

    for (int q = 0; q < NPH; ++q) {
        const int cur = q & 1;

        // T14: issue next-phase loads early; consumed after the MFMA cluster
        float4 p0, p1;
        if (q < NPH - 1) {
            p0 = *(const float4*)(Asrc + (q + 1) * KQ);
            p1 = *(const float4*)(Asrc + (q + 1) * KQ + 4);
        }

        // ---- compute phase q: 4 k-steps of 32, 16 MFMA each ----
        #pragma unroll 2
        for (int kk = 0; kk < KQ / 32; ++kk) {
            const int k0 = kk * 32 + lhi * 8;
            short8 af[4];
            #pragma unroll
            for (int rf = 0; rf < 4; ++rf) {
                int row = rf * 16 + l15;
                af[rf] = *(const short8*)(&As[cur][row * KQ + (k0 ^ ((row & 7) << 3))]);
            }
            short8 bfr[4];
            #pragma unroll
            for (int cf = 0; cf < 4; ++cf) {
                int e = e0 + cf * 16 + l15;
                bfr[cf] = *(const short8*)(Wb + (size_t)e * 1024 + q * KQ + k0);
            }
            #pragma unroll
            for (int rf = 0; rf < 4; ++rf)
                #pragma unroll
                for (int cf = 0; cf < 4; ++cf)
                    acc[rf][cf] = __builtin_amdgcn_mfma_f32_16x16x32_bf16(
                        af[rf], bfr[cf], acc[rf][cf], 0, 0, 0);
        }

        // T14 write-late: convert and park next phase into the other buffer
        if (q < NPH - 1) {
            short8 pk;
            pk[0] = (short)f2bf(p0.x); pk[1] = (short)f2bf(p0.y);
            pk[2] = (short)f2bf(p0.z); pk[3] = (short)f2bf(p0.w);
            pk[4] = (short)f2bf(p1.x); pk[5] = (short)f2bf(p1.y);
            pk[6] = (short)f2bf(p1.z); pk[7] = (short)f2bf(p1.w);
            *(short8*)(&As[cur ^ 1][sidx]) = pk;
        }
        __syncthreads();
    }

    // ---- epilogue: tanh + Va-weighted reduction over this wave's 64 cols ----
    // C/D layout (m89-verified): col = lane&15, row = (lane>>4)*4 + reg
    float sp[4][4];
    #pragma unroll
    for (int rf = 0; rf < 4; ++rf)
        #pragma unroll
        for (int j = 0; j < 4; ++j) sp[rf][j] = 0.f;

    #pragma unroll
    for (int cf = 0; cf < 4; ++cf) {
        int e = e0 + cf * 16 + l15;
        float offv = off[b * D_DIM + e];
        float vav  = Va[e];
        #pragma unroll
        for (int rf = 0; rf < 4; ++rf)
            #pragma unroll
            for (int j = 0; j < 4; ++j) {
                float x = acc[rf][cf][j] + offv;
                sp[rf][j] += fast_tanh(x) * vav;
            }
    }

    #pragma unroll
    for (int rf = 0; rf < 4; ++rf)
        #pragma unroll
        for (int j = 0; j < 4; ++j) {
            float v = sp[rf][j];
            v += __shfl_xor(v, 1, 64);
            v += __shfl_xor(v, 2, 64);
            v += __shfl_xor(v, 4, 64);
            v += __shfl_xor(v, 8, 64);
            if (l15 == 0) atomicAdd(&score_lds[rf * 16 + lhi * 4 + j], v);
        }
    __syncthreads();

    if (t < 64) scores[row0 + t] = score_lds[t];   // Va_b cancels in softmax
}

// ---------------------------------------------------------------------------
// Masked softmax over S=4096 per batch row. One block per b.
__global__ __launch_bounds__(256) void softmax_kernel(
        const float* __restrict__ scores, const void* __restrict__ mask,
        const int* __restrict__ flag, float* __restrict__ out) {
    __shared__ float red[4];
    const int b = blockIdx.x, t = threadIdx.x;
    const float* s = scores + (size_t)b * S_DIM;
    const int mode8 = flag[0];

    float v[16];
    float mx = -INFINITY;
    if (mode8) {
        const unsigned char* m = (const unsigned char*)mask + (size_t)b * S_DIM;
        #pragma unroll
        for (int i = 0; i < 16; ++i) {
            int idx = i * 256 + t;
            v[i] = m[idx] ? s[idx] : -INFINITY;
            mx = fmaxf(mx, v[i]);
        }
    } else {
        const int* m = (const int*)mask + (size_t)b * S_DIM;
        #pragma unroll
        for (int i = 0; i < 16; ++i) {
            int idx = i * 256 + t;
            v[i] = m[idx] ? s[idx] : -INFINITY;
            mx = fmaxf(mx, v[i]);
        }
    }
    #pragma unroll
    for (int k = 1; k <= 32; k <<= 1) mx = fmaxf(mx, __shfl_xor(mx, k, 64));
    if ((t & 63) == 0) red[t >> 6] = mx;
    __syncthreads();
    mx = fmaxf(fmaxf(red[0], red[1]), fmaxf(red[2], red[3]));
    __syncthreads();

    float sum = 0.f;
    #pragma unroll
    for (int i = 0; i < 16; ++i) {
        v[i] = __expf(v[i] - mx);     // exp(-inf)=0 for masked slots
        sum += v[i];
    }
    #pragma unroll
    for (int k = 1; k <= 32; k <<= 1) sum += __shfl_xor(sum, k, 64);
    if ((t & 63) == 0) red[t >> 6] = sum;
    __syncthreads();
    sum = red[0] + red[1] + red[2] + red[3];
    float inv = 1.f / sum;
    #pragma unroll
    for (int i = 0; i < 16; ++i) out[(size_t)b * S_DIM + i * 256 + t] = v[i] * inv;
}

// ---------------------------------------------------------------------------
extern "C" void kernel_launch(void* const* d_in, const int* in_sizes, int n_in,
                              void* d_out, int out_size, void* d_ws, size_t ws_size,
                              hipStream_t stream) {
    const float* enc  = (const float*)d_in[0];   // [32][4096][1024]
    const float* dech = (const float*)d_in[1];   // [1][32][1024]
    const void*  mask = d_in[2];                 // [32][4096] bool-or-int32
    const float* Wa_w = (const float*)d_in[3];   // [1024][1024]
    const float* Wa_b = (const float*)d_in[4];   // [1024]
    const float* Ua_w = (const float*)d_in[5];   // [1024][1024]
    const float* Ua_b = (const float*)d_in[6];   // [1024]
    const float* Va_w = (const float*)d_in[7];   // [1][1024]
    // d_in[8] = Va_b: constant shift -> cancels in softmax.
    float* out = (float*)d_out;

    char* ws = (char*)d_ws;
    unsigned short* Wb = (unsigned short*)ws;                       // 2 MiB
    float* off    = (float*)(ws + (1u << 21));                      // 128 KiB
    float* scores = (float*)(ws + (1u << 21) + (1u << 17));         // 512 KiB
    int*   flag   = (int*)(ws + (1u << 21) + (1u << 17) + (1u << 19));

    hipLaunchKernelGGL(mask_detect_kernel, dim3(1), dim3(256), 0, stream,
                       (const unsigned int*)mask, flag);
    hipLaunchKernelGGL(wconv_kernel, dim3(1024), dim3(256), 0, stream, Wa_w, Wb);
    hipLaunchKernelGGL(off_kernel, dim3(8192), dim3(256), 0, stream,
                       dech, Ua_w, Ua_b, Wa_b, off);
    hipLaunchKernelGGL(score_kernel, dim3(2048), dim3(1024), 0, stream,
                       enc, Wb, off, Va_w, scores);
    hipLaunchKernelGGL(softmax_kernel, dim3(B_DIM), dim3(256), 0, stream,
                       scores, mask, flag, out);
}

// Round 3
// 376.656 us; speedup vs baseline: 1.6480x; 1.6480x over previous
//
#include <hip/hip_runtime.h>
#include <math.h>

// Problem shape (fixed): B=32, S=4096, D=1024, L=1
#define D_DIM 1024
#define S_DIM 4096
#define B_DIM 32
#define M_TOTAL (B_DIM * S_DIM)   // 131072 rows

#define KQ   128                  // K per pipeline phase
#define NPH  8                    // phases (8*128 = 1024)

using short8 = __attribute__((ext_vector_type(8))) short;
using f32x4  = __attribute__((ext_vector_type(4))) float;

// fp32 -> bf16, round-to-nearest-even
static __device__ __forceinline__ unsigned short f2bf(float x) {
    unsigned int u = __float_as_uint(x);
    u += 0x7fffu + ((u >> 16) & 1u);
    return (unsigned short)(u >> 16);
}

// tanh via exp2-backed __expf; ~1e-6 abs err (we need ~1e-3)
static __device__ __forceinline__ float fast_tanh(float x) {
    float e2 = __expf(2.0f * x);
    return 1.0f - 2.0f * __builtin_amdgcn_rcpf(e2 + 1.0f);
}

// ---------------------------------------------------------------------------
// Detect attn_mask dtype: int32 (0/1 -> high bytes of every word are 0)
// vs. bool/uint8 (random 0/1 bytes -> some high byte nonzero).
__global__ __launch_bounds__(256) void mask_detect_kernel(
        const unsigned int* __restrict__ m, int* __restrict__ flag) {
    __shared__ unsigned int red[4];
    int t = threadIdx.x;
    unsigned int acc = 0;
    for (int i = t; i < 32768; i += 256) acc |= (m[i] & 0xFFFFFF00u);
    #pragma unroll
    for (int k = 1; k <= 32; k <<= 1) acc |= __shfl_xor(acc, k, 64);
    if ((t & 63) == 0) red[t >> 6] = acc;
    __syncthreads();
    if (t == 0) flag[0] = ((red[0] | red[1] | red[2] | red[3]) != 0) ? 1 : 0;
}

// ---------------------------------------------------------------------------
// Convert Wa_w [1024][1024] fp32 -> bf16 in FRAGMENT-TILED layout:
//   Wt[((et*32 + kc)*64 + lane)*8 + j] = bf16( W[et*16 + (lane&15)]
//                                              [kc*32 + (lane>>4)*8 + j] )
// so a wave's B-fragment load for (16-col tile et, 32-k chunk kc) is one
// fully-coalesced 16B/lane (1 KiB/instruction) read — no 2KB-stride gather.
__global__ __launch_bounds__(256) void wconv_kernel(
        const float* __restrict__ W, unsigned short* __restrict__ Wt) {
    int tid  = blockIdx.x * 256 + threadIdx.x;   // 0..131071, one short8 each
    int lane = tid & 63;
    int kc   = (tid >> 6) & 31;
    int et   = tid >> 11;
    int e = et * 16 + (lane & 15);
    int k = kc * 32 + (lane >> 4) * 8;
    const float* src = W + (size_t)e * D_DIM + k;
    float4 v0 = *(const float4*)(src);
    float4 v1 = *(const float4*)(src + 4);
    short8 pk;
    pk[0] = (short)f2bf(v0.x); pk[1] = (short)f2bf(v0.y);
    pk[2] = (short)f2bf(v0.z); pk[3] = (short)f2bf(v0.w);
    pk[4] = (short)f2bf(v1.x); pk[5] = (short)f2bf(v1.y);
    pk[6] = (short)f2bf(v1.z); pk[7] = (short)f2bf(v1.w);
    *(short8*)(Wt + (size_t)tid * 8) = pk;
}

// ---------------------------------------------------------------------------
// off[b][e] = sum_d h[0][b][d]*Ua_w[e][d] + Ua_b[e] + Wa_b[e]
__global__ __launch_bounds__(256) void off_kernel(
        const float* __restrict__ h, const float* __restrict__ Uw,
        const float* __restrict__ Ub, const float* __restrict__ Wab,
        float* __restrict__ off) {
    int wg   = blockIdx.x * 4 + (threadIdx.x >> 6);
    int lane = threadIdx.x & 63;
    int b = wg >> 10, e = wg & 1023;
    const float4* h4 = (const float4*)(h + (size_t)b * D_DIM);
    const float4* u4 = (const float4*)(Uw + (size_t)e * D_DIM);
    float s = 0.f;
    #pragma unroll
    for (int c = 0; c < 4; ++c) {
        float4 a = h4[c * 64 + lane];
        float4 w = u4[c * 64 + lane];
        s += a.x * w.x + a.y * w.y + a.z * w.z + a.w * w.w;
    }
    #pragma unroll
    for (int m = 32; m; m >>= 1) s += __shfl_xor(s, m, 64);
    if (lane == 0) off[b * D_DIM + e] = s + Ub[e] + Wab[e];
}

// ---------------------------------------------------------------------------
// Fused: scores[row] = sum_e Va[e] * tanh( (A@W^T)[row][e] + off[b][e] )
//
// 16 waves (1024 thr); block = 64 rows x 1024 cols; wave w owns cols
// [w*64, w*64+64). K pipelined in 8 phases of 128 through a 2x16KB
// double-buffered swizzled LDS A-panel (T14 issue-early/write-late).
// B-fragments stream coalesced from the tiled bf16 W (L2-resident).
__global__ __launch_bounds__(1024, 4) void score_kernel(
        const float* __restrict__ A,            // [M][1024] fp32
        const unsigned short* __restrict__ Wt,  // tiled bf16 (see wconv)
        const float* __restrict__ off,          // [32][1024]
        const float* __restrict__ Va,           // [1024]
        float* __restrict__ scores)             // [M]
{
    __shared__ short As[2][64 * KQ];    // 2 x 16 KiB, XOR-swizzled rows
    __shared__ float score_lds[64];

    const int t    = threadIdx.x;
    const int row0 = blockIdx.x * 64;
    const int b    = row0 >> 12;        // 4096 rows per batch

    if (t < 64) score_lds[t] = 0.f;

    const int wave = t >> 6, lane = t & 63;
    const int l15 = lane & 15, lhi = lane >> 4;
    const int e0 = wave * 64;

    // coalesced B base: fragment (cf, kglob) lives at +(cf*32 + kglob)*512
    const unsigned short* WtB = Wt + ((size_t)wave * 4 * 32) * 512 + (size_t)lane * 8;

    // per-thread staging slot: one short8 per phase
    const int sr = t >> 4;              // row 0..63
    const int sk = (t & 15) * 8;        // k-base 0..120
    const float* Asrc = A + (size_t)(row0 + sr) * D_DIM + sk;
    const int sidx = sr * KQ + (sk ^ ((sr & 7) << 3));   // ushort units

    f32x4 acc[4][4];
    #pragma unroll
    for (int rf = 0; rf < 4; ++rf)
        #pragma unroll
        for (int cf = 0; cf < 4; ++cf) acc[rf][cf] = (f32x4){0.f, 0.f, 0.f, 0.f};

    // ---- prologue: stage phase 0 ----
    {
        float4 v0 = *(const float4*)(Asrc + 0);
        float4 v1 = *(const float4*)(Asrc + 4);
        short8 pk;
        pk[0] = (short)f2bf(v0.x); pk[1] = (short)f2bf(v0.y);
        pk[2] = (short)f2bf(v0.z); pk[3] = (short)f2bf(v0.w);
        pk[4] = (short)f2bf(v1.x); pk[5] = (short)f2bf(v1.y);
        pk[6] = (short)f2bf(v1.z); pk[7] = (short)f2bf(v1.w);
        *(short8*)(&As[0][sidx]) = pk;
    }
    __syncthreads();

    for (int q = 0; q < NPH; ++q) {
        const int cur = q & 1;

        // T14: issue next-phase loads early; consumed after the MFMA cluster
        float4 p0, p1;
        if (q < NPH - 1) {
            p0 = *(const float4*)(Asrc + (q + 1) * KQ);
            p1 = *(const float4*)(Asrc + (q + 1) * KQ + 4);
        }

        // ---- compute phase q: 4 k-steps of 32, 16 MFMA each ----
        #pragma unroll
        for (int kk = 0; kk < KQ / 32; ++kk) {
            const int k0 = kk * 32 + lhi * 8;
            const int kglob = q * 4 + kk;
            short8 af[4];
            #pragma unroll
            for (int rf = 0; rf < 4; ++rf) {
                int row = rf * 16 + l15;
                af[rf] = *(const short8*)(&As[cur][row * KQ + (k0 ^ ((row & 7) << 3))]);
            }
            short8 bfr[4];
            #pragma unroll
            for (int cf = 0; cf < 4; ++cf)
                bfr[cf] = *(const short8*)(WtB + (size_t)(cf * 32 + kglob) * 512);
            __builtin_amdgcn_s_setprio(1);
            #pragma unroll
            for (int rf = 0; rf < 4; ++rf)
                #pragma unroll
                for (int cf = 0; cf < 4; ++cf)
                    acc[rf][cf] = __builtin_amdgcn_mfma_f32_16x16x32_bf16(
                        af[rf], bfr[cf], acc[rf][cf], 0, 0, 0);
            __builtin_amdgcn_s_setprio(0);
        }

        // T14 write-late: convert and park next phase into the other buffer
        if (q < NPH - 1) {
            short8 pk;
            pk[0] = (short)f2bf(p0.x); pk[1] = (short)f2bf(p0.y);
            pk[2] = (short)f2bf(p0.z); pk[3] = (short)f2bf(p0.w);
            pk[4] = (short)f2bf(p1.x); pk[5] = (short)f2bf(p1.y);
            pk[6] = (short)f2bf(p1.z); pk[7] = (short)f2bf(p1.w);
            *(short8*)(&As[cur ^ 1][sidx]) = pk;
        }
        __syncthreads();
    }

    // ---- epilogue: tanh + Va-weighted reduction over this wave's 64 cols ----
    // C/D layout (m89-verified): col = lane&15, row = (lane>>4)*4 + reg
    float sp[4][4];
    #pragma unroll
    for (int rf = 0; rf < 4; ++rf)
        #pragma unroll
        for (int j = 0; j < 4; ++j) sp[rf][j] = 0.f;

    #pragma unroll
    for (int cf = 0; cf < 4; ++cf) {
        int e = e0 + cf * 16 + l15;
        float offv = off[b * D_DIM + e];
        float vav  = Va[e];
        #pragma unroll
        for (int rf = 0; rf < 4; ++rf)
            #pragma unroll
            for (int j = 0; j < 4; ++j) {
                float x = acc[rf][cf][j] + offv;
                sp[rf][j] += fast_tanh(x) * vav;
            }
    }

    #pragma unroll
    for (int rf = 0; rf < 4; ++rf)
        #pragma unroll
        for (int j = 0; j < 4; ++j) {
            float v = sp[rf][j];
            v += __shfl_xor(v, 1, 64);
            v += __shfl_xor(v, 2, 64);
            v += __shfl_xor(v, 4, 64);
            v += __shfl_xor(v, 8, 64);
            if (l15 == 0) atomicAdd(&score_lds[rf * 16 + lhi * 4 + j], v);
        }
    __syncthreads();

    if (t < 64) scores[row0 + t] = score_lds[t];   // Va_b cancels in softmax
}

// ---------------------------------------------------------------------------
// Masked softmax over S=4096 per batch row. One block per b.
__global__ __launch_bounds__(256) void softmax_kernel(
        const float* __restrict__ scores, const void* __restrict__ mask,
        const int* __restrict__ flag, float* __restrict__ out) {
    __shared__ float red[4];
    const int b = blockIdx.x, t = threadIdx.x;
    const float* s = scores + (size_t)b * S_DIM;
    const int mode8 = flag[0];

    float v[16];
    float mx = -INFINITY;
    if (mode8) {
        const unsigned char* m = (const unsigned char*)mask + (size_t)b * S_DIM;
        #pragma unroll
        for (int i = 0; i < 16; ++i) {
            int idx = i * 256 + t;
            v[i] = m[idx] ? s[idx] : -INFINITY;
            mx = fmaxf(mx, v[i]);
        }
    } else {
        const int* m = (const int*)mask + (size_t)b * S_DIM;
        #pragma unroll
        for (int i = 0; i < 16; ++i) {
            int idx = i * 256 + t;
            v[i] = m[idx] ? s[idx] : -INFINITY;
            mx = fmaxf(mx, v[i]);
        }
    }
    #pragma unroll
    for (int k = 1; k <= 32; k <<= 1) mx = fmaxf(mx, __shfl_xor(mx, k, 64));
    if ((t & 63) == 0) red[t >> 6] = mx;
    __syncthreads();
    mx = fmaxf(fmaxf(red[0], red[1]), fmaxf(red[2], red[3]));
    __syncthreads();

    float sum = 0.f;
    #pragma unroll
    for (int i = 0; i < 16; ++i) {
        v[i] = __expf(v[i] - mx);     // exp(-inf)=0 for masked slots
        sum += v[i];
    }
    #pragma unroll
    for (int k = 1; k <= 32; k <<= 1) sum += __shfl_xor(sum, k, 64);
    if ((t & 63) == 0) red[t >> 6] = sum;
    __syncthreads();
    sum = red[0] + red[1] + red[2] + red[3];
    float inv = 1.f / sum;
    #pragma unroll
    for (int i = 0; i < 16; ++i) out[(size_t)b * S_DIM + i * 256 + t] = v[i] * inv;
}

// ---------------------------------------------------------------------------
extern "C" void kernel_launch(void* const* d_in, const int* in_sizes, int n_in,
                              void* d_out, int out_size, void* d_ws, size_t ws_size,
                              hipStream_t stream) {
    const float* enc  = (const float*)d_in[0];   // [32][4096][1024]
    const float* dech = (const float*)d_in[1];   // [1][32][1024]
    const void*  mask = d_in[2];                 // [32][4096] bool-or-int32
    const float* Wa_w = (const float*)d_in[3];   // [1024][1024]
    const float* Wa_b = (const float*)d_in[4];   // [1024]
    const float* Ua_w = (const float*)d_in[5];   // [1024][1024]
    const float* Ua_b = (const float*)d_in[6];   // [1024]
    const float* Va_w = (const float*)d_in[7];   // [1][1024]
    // d_in[8] = Va_b: constant shift -> cancels in softmax.
    float* out = (float*)d_out;

    char* ws = (char*)d_ws;
    unsigned short* Wt = (unsigned short*)ws;                       // 2 MiB tiled
    float* off    = (float*)(ws + (1u << 21));                      // 128 KiB
    float* scores = (float*)(ws + (1u << 21) + (1u << 17));         // 512 KiB
    int*   flag   = (int*)(ws + (1u << 21) + (1u << 17) + (1u << 19));

    hipLaunchKernelGGL(mask_detect_kernel, dim3(1), dim3(256), 0, stream,
                       (const unsigned int*)mask, flag);
    hipLaunchKernelGGL(wconv_kernel, dim3(512), dim3(256), 0, stream, Wa_w, Wt);
    hipLaunchKernelGGL(off_kernel, dim3(8192), dim3(256), 0, stream,
                       dech, Ua_w, Ua_b, Wa_b, off);
    hipLaunchKernelGGL(score_kernel, dim3(2048), dim3(1024), 0, stream,
                       enc, Wt, off, Va_w, scores);
    hipLaunchKernelGGL(softmax_kernel, dim3(B_DIM), dim3(256), 0, stream,
                       scores, mask, flag, out);
}